// Round 9
// baseline (130.589 us; speedup 1.0000x reference)
//
#include <hip/hip_runtime.h>
#include <hip/hip_bf16.h>

#define SS 2048
#define DD 128
#define BB 16
#define LDST 136  // xs staging pad (ushorts)
#define SCT 268   // sc stride: 4-way max on frag-order epilogue reads

typedef short bf16x8 __attribute__((ext_vector_type(8)));
typedef float f32x4 __attribute__((ext_vector_type(4)));
typedef unsigned short ushort_t;

#define SB0() __builtin_amdgcn_sched_barrier(0)
#define WAITV(n) asm volatile("s_waitcnt vmcnt(" #n ")" ::: "memory")

__device__ __forceinline__ unsigned short f2bf(float f) {
  union { float f; unsigned u; } v; v.f = f;
  unsigned r = v.u + 0x7fffu + ((v.u >> 16) & 1u);  // RNE
  return (unsigned short)(r >> 16);
}
__device__ __forceinline__ float fexp2(float x) { return __builtin_amdgcn_exp2f(x); }

// Fragment-major layout: chunk index ((G*4 + ks)*64 + lane), 16 B each.
// G = global 16-row group (b*128 + g), lane = quad*16 + lq holds
// rows[G*16+lq], cols[ks*32+quad*8 .. +8].

// ---------------------------------------------------------------------------
// wprep: wt_g = [Wq^T * log2e/sqrt(U) ; Wk^T] bf16 [256][128]. grid 128.
// ---------------------------------------------------------------------------
__global__ __launch_bounds__(256) void wprep(
    const float* __restrict__ Wq, const float* __restrict__ Wk,
    ushort_t* __restrict__ wt_g) {
  int idx = blockIdx.x * 256 + threadIdx.x;  // 0..32767
  int r = idx & 16383, uu = r >> 7, d = r & 127;
  if (idx < 16384)
    wt_g[uu * 128 + d] = f2bf(Wq[d * 128 + uu] * 0.1275174346f);  // log2e/sqrt(128)
  else
    wt_g[(uu + 128) * 128 + d] = f2bf(Wk[d * 128 + uu]);
}

// ---------------------------------------------------------------------------
// qk_gemm: [q|k] = bf16(x) @ wt_g^T, output in FRAG-MAJOR layout.
// grid 512 (64 rows/block), block 256.  (unchanged)
// ---------------------------------------------------------------------------
__global__ __launch_bounds__(256, 2) void qk_gemm(
    const float* __restrict__ x, const ushort_t* __restrict__ wt_g,
    uint4* __restrict__ qF, uint4* __restrict__ kF) {
  __shared__ ushort_t xs[64 * LDST];
  __shared__ ushort_t sc[64 * SCT];
  const int tid = threadIdx.x, wave = tid >> 6, lane = tid & 63;
  const int lq = lane & 15, quad = lane >> 4;
  const int m0 = blockIdx.x * 64;

#pragma unroll
  for (int i = 0; i < 8; ++i) {  // stage x: 64x128 fp32 -> bf16
    int idx = i * 256 + tid;
    int row = idx >> 5, c4 = (idx & 31) * 4;
    const float4 v = *(const float4*)(x + (size_t)(m0 + row) * DD + c4);
    ushort4 h;
    h.x = f2bf(v.x); h.y = f2bf(v.y); h.z = f2bf(v.z); h.w = f2bf(v.w);
    *(ushort4*)(&xs[row * LDST + c4]) = h;
  }
  bf16x8 wf[4][4];  // wave's 64 output cols, K=128
#pragma unroll
  for (int nt = 0; nt < 4; ++nt)
#pragma unroll
    for (int ks = 0; ks < 4; ++ks)
      wf[nt][ks] = *(const bf16x8*)(wt_g + (wave * 64 + nt * 16 + lq) * 128 + ks * 32 + quad * 8);
  __syncthreads();

  f32x4 acc[4][4];
#pragma unroll
  for (int mt = 0; mt < 4; ++mt)
#pragma unroll
    for (int nt = 0; nt < 4; ++nt) acc[mt][nt] = (f32x4){0.f, 0.f, 0.f, 0.f};
#pragma unroll
  for (int mt = 0; mt < 4; ++mt) {
    bf16x8 af[4];
#pragma unroll
    for (int ks = 0; ks < 4; ++ks)
      af[ks] = *(const bf16x8*)(&xs[(mt * 16 + lq) * LDST + ks * 32 + quad * 8]);
#pragma unroll
    for (int nt = 0; nt < 4; ++nt)
#pragma unroll
      for (int ks = 0; ks < 4; ++ks)
        acc[mt][nt] = __builtin_amdgcn_mfma_f32_16x16x32_bf16(af[ks], wf[nt][ks], acc[mt][nt], 0, 0, 0);
  }
#pragma unroll
  for (int mt = 0; mt < 4; ++mt)
#pragma unroll
    for (int nt = 0; nt < 4; ++nt)
#pragma unroll
      for (int r = 0; r < 4; ++r)
        sc[(mt * 16 + quad * 4 + r) * SCT + wave * 64 + nt * 16 + lq] = f2bf(acc[mt][nt][r]);
  __syncthreads();
#pragma unroll
  for (int i = 0; i < 8; ++i) {
    int c = i * 256 + tid;                 // 0..2047
    int lane_c = c & 63, ks_c = (c >> 6) & 3, g_c = (c >> 8) & 3, isk = c >> 10;
    int li = lane_c & 15, qd = lane_c >> 4;
    int col = isk * 128 + ks_c * 32 + qd * 8;
    uint4 v = *(const uint4*)(&sc[(g_c * 16 + li) * SCT + col]);
    size_t G = (size_t)blockIdx.x * 4 + g_c;
    uint4* dst = isk ? kF : qF;
    dst[(G * 4 + ks_c) * 64 + lane_c] = v;
  }
}

// ---------------------------------------------------------------------------
// attn pass 1 & 2 — L1-SHARED K: waves partition i, read the SAME groups.
//
// R8 post-mortem: XCD-chunking made the stream L2-resident (FETCH 70->8.4
// MB) and the forced vmcnt pipeline changed codegen (VGPR 76) -- time
// UNCHANGED. With R4 (occupancy-invariant) and R7 (LDS-share slower via
// barriers), the surviving model is the ~12.6 TB/s L2->CU delivery cap
// on the 268 MB/pass K stream. This version cuts L2 bytes WITHOUT
// barriers-per-step: the block's 4 waves each own 64 i-rows (af in regs,
// R8's exact no-spill shape) and read the SAME K group sequence -> 3 of
// 4 requests hit the per-CU L1 (32 KB ~ 8 groups; raw s_barrier every 8
// groups bounds drift, no counter drain). L2 bytes/pass: 268 -> ~64 MB
// K + 32 MB Q. Per-wave instruction stream is IDENTICAL to R8 -- a pure
// bytes-vs-instructions discriminator. j split 4-ways (grid 512) -> l
// crosses blocks -> split kernels (R4-proven), l via atomicAdd.
// ---------------------------------------------------------------------------
__device__ __forceinline__ void attn_decode(int bx, int& b, int& ii, int& jq) {
  int xcd = bx & 7, s = bx >> 3;          // dispatcher: wgid%8 -> XCD
  b = xcd + ((s >> 5) << 3);              // XCD x hosts batches x, x+8
  int r = s & 31;
  ii = r >> 2;                            // i-block 0..7 (256 rows)
  jq = r & 3;                             // j-quarter 0..3 (32 groups)
}

__global__ __launch_bounds__(256, 2) void attn_p1(
    const uint4* __restrict__ qF, const uint4* __restrict__ kF,
    float* __restrict__ l) {
  int b, ii, jq;
  attn_decode(blockIdx.x, b, ii, jq);
  const int tid = threadIdx.x, wave = tid >> 6, lane = tid & 63;
  const int lq = lane & 15, quad = lane >> 4;

  const bf16x8* qc = (const bf16x8*)qF;
  bf16x8 af[4][4];  // this wave's 64 i-rows: groups ii*16 + wave*4 + mt
#pragma unroll
  for (int mt = 0; mt < 4; ++mt)
#pragma unroll
    for (int ks = 0; ks < 4; ++ks)
      af[mt][ks] = qc[((size_t)(b * 128 + ii * 16 + wave * 4 + mt) * 4 + ks) * 64 + lane];

  const bf16x8* kb = (const bf16x8*)kF + (size_t)b * 128 * 4 * 64 + lane;
  auto loadg = [&](bf16x8 (&f)[4], int g) {
#pragma unroll
    for (int ks = 0; ks < 4; ++ks) f[ks] = kb[((size_t)g * 4 + ks) * 64];
  };

  const f32x4 z4 = {0.f, 0.f, 0.f, 0.f};
  auto mfma16 = [&](f32x4 (&a)[4], bf16x8 (&f)[4]) {
    __builtin_amdgcn_s_setprio(1);
#pragma unroll
    for (int mt = 0; mt < 4; ++mt)
      a[mt] = __builtin_amdgcn_mfma_f32_16x16x32_bf16(af[mt][0], f[0], z4, 0, 0, 0);
#pragma unroll
    for (int ks = 1; ks < 4; ++ks)
#pragma unroll
      for (int mt = 0; mt < 4; ++mt)
        a[mt] = __builtin_amdgcn_mfma_f32_16x16x32_bf16(af[mt][ks], f[ks], a[mt], 0, 0, 0);
    __builtin_amdgcn_s_setprio(0);
  };

  float rowsum[4][4];
#pragma unroll
  for (int mt = 0; mt < 4; ++mt)
#pragma unroll
    for (int r = 0; r < 4; ++r) rowsum[mt][r] = 0.f;
  auto proc1 = [&](f32x4 (&a)[4]) {
#pragma unroll
    for (int mt = 0; mt < 4; ++mt)
#pragma unroll
      for (int r = 0; r < 4; ++r) rowsum[mt][r] += fexp2(a[mt][r]);
  };

  const int g0 = jq * 32;  // ALL 4 waves read the same sequence
  bf16x8 fA[4], fB[4];
  f32x4 a[4];

  loadg(fA, g0);
  loadg(fB, g0 + 1);                     // 8 loads in flight
  for (int m = 0; m < 30; m += 2) {
    if ((m & 7) == 0) __builtin_amdgcn_s_barrier();  // bound wave drift (L1 reuse)
    WAITV(4); SB0();
    mfma16(a, fA);
    loadg(fA, g0 + m + 2); SB0();
    proc1(a);
    WAITV(4); SB0();
    mfma16(a, fB);
    loadg(fB, g0 + m + 3); SB0();
    proc1(a);
  }
  WAITV(4); SB0(); mfma16(a, fA); SB0(); proc1(a);
  WAITV(0); SB0(); mfma16(a, fB); SB0(); proc1(a);

  // reduce over the 16 j-cols (lq lanes); each i-row owned by one wave
#pragma unroll
  for (int d2 = 1; d2 <= 8; d2 <<= 1)
#pragma unroll
    for (int mt = 0; mt < 4; ++mt)
#pragma unroll
      for (int r = 0; r < 4; ++r)
        rowsum[mt][r] += __shfl_xor(rowsum[mt][r], d2, 64);
  if (lq == 0) {
#pragma unroll
    for (int mt = 0; mt < 4; ++mt)
#pragma unroll
      for (int r = 0; r < 4; ++r)
        atomicAdd(&l[b * SS + (ii * 16 + wave * 4 + mt) * 16 + quad * 4 + r],
                  rowsum[mt][r]);
  }
}

__global__ __launch_bounds__(256, 2) void attn_p2(
    const uint4* __restrict__ qF, const uint4* __restrict__ kF,
    const float* __restrict__ t, const float* __restrict__ theta,
    const float* __restrict__ mu, const float* __restrict__ l,
    float* __restrict__ w) {
  int b, ii, jq;
  attn_decode(blockIdx.x, b, ii, jq);
  const int tid = threadIdx.x, wave = tid >> 6, lane = tid & 63;
  const int lq = lane & 15, quad = lane >> 4;
  __shared__ float c_lds[256];

  {  // c_i = sigmoid(theta - mu*t) / l_i for this block's 256 rows
    int gi = ii * 256 + tid;
    float z = theta[gi] - mu[gi] * t[b * SS + gi];
    float tf = 1.f / (1.f + fexp2(-z * 1.44269504f));
    c_lds[tid] = tf / l[b * SS + gi];
  }

  const bf16x8* qc = (const bf16x8*)qF;
  bf16x8 af[4][4];
#pragma unroll
  for (int mt = 0; mt < 4; ++mt)
#pragma unroll
    for (int ks = 0; ks < 4; ++ks)
      af[mt][ks] = qc[((size_t)(b * 128 + ii * 16 + wave * 4 + mt) * 4 + ks) * 64 + lane];

  const bf16x8* kb = (const bf16x8*)kF + (size_t)b * 128 * 4 * 64 + lane;
  auto loadg = [&](bf16x8 (&f)[4], int g) {
#pragma unroll
    for (int ks = 0; ks < 4; ++ks) f[ks] = kb[((size_t)g * 4 + ks) * 64];
  };

  __syncthreads();  // c_lds visible
  float creg[4][4];
#pragma unroll
  for (int mt = 0; mt < 4; ++mt)
#pragma unroll
    for (int r = 0; r < 4; ++r)
      creg[mt][r] = c_lds[(wave * 4 + mt) * 16 + quad * 4 + r];

  const f32x4 z4 = {0.f, 0.f, 0.f, 0.f};
  auto mfma16 = [&](f32x4 (&a)[4], bf16x8 (&f)[4]) {
    __builtin_amdgcn_s_setprio(1);
#pragma unroll
    for (int mt = 0; mt < 4; ++mt)
      a[mt] = __builtin_amdgcn_mfma_f32_16x16x32_bf16(af[mt][0], f[0], z4, 0, 0, 0);
#pragma unroll
    for (int ks = 1; ks < 4; ++ks)
#pragma unroll
      for (int mt = 0; mt < 4; ++mt)
        a[mt] = __builtin_amdgcn_mfma_f32_16x16x32_bf16(af[mt][ks], f[ks], a[mt], 0, 0, 0);
    __builtin_amdgcn_s_setprio(0);
  };
  auto proc2 = [&](f32x4 (&a)[4], int g) {
    float cs = 0.f;
#pragma unroll
    for (int mt = 0; mt < 4; ++mt)
#pragma unroll
      for (int r = 0; r < 4; ++r) cs = fmaf(creg[mt][r], fexp2(a[mt][r]), cs);
    cs += __shfl_xor(cs, 16, 64);
    cs += __shfl_xor(cs, 32, 64);
    if (lane < 16) atomicAdd(&w[b * SS + g * 16 + lane], cs);
  };

  const int g0 = jq * 32;
  bf16x8 fA[4], fB[4];
  f32x4 a[4];

  loadg(fA, g0);
  loadg(fB, g0 + 1);
  for (int m = 0; m < 30; m += 2) {
    if ((m & 7) == 0) __builtin_amdgcn_s_barrier();
    WAITV(4); SB0();
    mfma16(a, fA);
    loadg(fA, g0 + m + 2); SB0();
    proc2(a, g0 + m);
    WAITV(4); SB0();
    mfma16(a, fB);
    loadg(fB, g0 + m + 3); SB0();
    proc2(a, g0 + m + 1);
  }
  WAITV(4); SB0(); mfma16(a, fA); SB0(); proc2(a, g0 + 30);
  WAITV(0); SB0(); mfma16(a, fB); SB0(); proc2(a, g0 + 31);
}

// ---------------------------------------------------------------------------
// finalize: v[b,d] = sum_j w[b,j] * x[b,j,d].  grid 512 (64 j per block).
// Vectorized float4 loads, tree reduce.
// ---------------------------------------------------------------------------
__global__ __launch_bounds__(256) void finalize(
    const float* __restrict__ x, const float* __restrict__ w,
    float* __restrict__ out) {
  const int b = blockIdx.x >> 5;
  const int j0 = (blockIdx.x & 31) * 64;
  const int tid = threadIdx.x;
  const int d4 = (tid & 31) * 4, jo = tid >> 5;  // 32 d-groups x 8 j-offsets
  float4 a0 = {0.f, 0.f, 0.f, 0.f}, a1 = {0.f, 0.f, 0.f, 0.f};
#pragma unroll
  for (int jj = 0; jj < 4; ++jj) {
    int ja = j0 + jj * 16 + jo, jb = ja + 8;
    float wa = w[b * SS + ja], wb = w[b * SS + jb];
    const float4 xa = *(const float4*)(x + ((size_t)b * SS + ja) * DD + d4);
    const float4 xb = *(const float4*)(x + ((size_t)b * SS + jb) * DD + d4);
    a0.x = fmaf(wa, xa.x, a0.x); a0.y = fmaf(wa, xa.y, a0.y);
    a0.z = fmaf(wa, xa.z, a0.z); a0.w = fmaf(wa, xa.w, a0.w);
    a1.x = fmaf(wb, xb.x, a1.x); a1.y = fmaf(wb, xb.y, a1.y);
    a1.z = fmaf(wb, xb.z, a1.z); a1.w = fmaf(wb, xb.w, a1.w);
  }
  __shared__ float4 red[256];
  float4 acc = {a0.x + a1.x, a0.y + a1.y, a0.z + a1.z, a0.w + a1.w};
  red[tid] = acc;
  __syncthreads();
  if (tid < 128) {
    float4 o = red[tid + 128];
    red[tid].x += o.x; red[tid].y += o.y; red[tid].z += o.z; red[tid].w += o.w;
  }
  __syncthreads();
  if (tid < 64) {
    float4 o = red[tid + 64];
    red[tid].x += o.x; red[tid].y += o.y; red[tid].z += o.z; red[tid].w += o.w;
  }
  __syncthreads();
  if (tid < 32) {
    float4 v = red[tid], o = red[tid + 32];
    v.x += o.x; v.y += o.y; v.z += o.z; v.w += o.w;
    atomicAdd(&out[b * DD + d4 + 0], v.x);
    atomicAdd(&out[b * DD + d4 + 1], v.y);
    atomicAdd(&out[b * DD + d4 + 2], v.z);
    atomicAdd(&out[b * DD + d4 + 3], v.w);
  }
}

extern "C" void kernel_launch(void* const* d_in, const int* in_sizes, int n_in,
                              void* d_out, int out_size, void* d_ws, size_t ws_size,
                              hipStream_t stream) {
  const float* x = (const float*)d_in[0];
  const float* t = (const float*)d_in[1];
  const float* Wq = (const float*)d_in[2];
  const float* Wk = (const float*)d_in[3];
  const float* theta = (const float*)d_in[4];
  const float* mu = (const float*)d_in[5];
  float* out = (float*)d_out;

  uint4* qF = (uint4*)d_ws;                             // 8.4 MB (frag-major)
  uint4* kF = qF + (size_t)2048 * 4 * 64;               // 8.4 MB (frag-major)
  ushort_t* wt_g = (ushort_t*)(kF + (size_t)2048 * 4 * 64);  // 64 KB
  float* w = (float*)(wt_g + 256 * 128);                // 128 KB
  float* l = w + (size_t)BB * SS;                       // 128 KB

  hipMemsetAsync(w, 0, (size_t)BB * SS * sizeof(float), stream);
  hipMemsetAsync(l, 0, (size_t)BB * SS * sizeof(float), stream);
  hipMemsetAsync(d_out, 0, (size_t)BB * DD * sizeof(float), stream);

  wprep<<<dim3(128), dim3(256), 0, stream>>>(Wq, Wk, wt_g);
  qk_gemm<<<dim3(512), dim3(256), 0, stream>>>(x, wt_g, qF, kF);
  attn_p1<<<dim3(512), dim3(256), 0, stream>>>(qF, kF, l);
  attn_p2<<<dim3(512), dim3(256), 0, stream>>>(qF, kF, t, theta, mu, l, w);
  finalize<<<dim3(512), dim3(256), 0, stream>>>(x, w, out);
}

// Round 10
// 129.514 us; speedup vs baseline: 1.0083x; 1.0083x over previous
//
#include <hip/hip_runtime.h>
#include <hip/hip_bf16.h>

#define SS 2048
#define DD 128
#define BB 16
#define LDST 136  // xs staging pad (ushorts)
#define SCT 268   // sc stride: 4-way max on frag-order epilogue reads

typedef short bf16x8 __attribute__((ext_vector_type(8)));
typedef float f32x4 __attribute__((ext_vector_type(4)));
typedef unsigned short ushort_t;

#define SB0() __builtin_amdgcn_sched_barrier(0)
#define WAITV(n) asm volatile("s_waitcnt vmcnt(" #n ")" ::: "memory")
// SGB masks (m137): MFMA=0x8, VALU=0x2
#define SGB_MFMA1_VALU2() \
  do { _Pragma("unroll") for (int _k = 0; _k < 16; ++_k) { \
    __builtin_amdgcn_sched_group_barrier(0x008, 1, 0); \
    __builtin_amdgcn_sched_group_barrier(0x002, 2, 0); } } while (0)

__device__ __forceinline__ unsigned short f2bf(float f) {
  union { float f; unsigned u; } v; v.f = f;
  unsigned r = v.u + 0x7fffu + ((v.u >> 16) & 1u);  // RNE
  return (unsigned short)(r >> 16);
}
__device__ __forceinline__ float fexp2(float x) { return __builtin_amdgcn_exp2f(x); }

// Fragment-major layout: chunk index ((G*4 + ks)*64 + lane), 16 B each.

// ---------------------------------------------------------------------------
// wprep: wt_g = [Wq^T * log2e/sqrt(U) ; Wk^T] bf16 [256][128]. grid 128.
// ---------------------------------------------------------------------------
__global__ __launch_bounds__(256) void wprep(
    const float* __restrict__ Wq, const float* __restrict__ Wk,
    ushort_t* __restrict__ wt_g) {
  int idx = blockIdx.x * 256 + threadIdx.x;  // 0..32767
  int r = idx & 16383, uu = r >> 7, d = r & 127;
  if (idx < 16384)
    wt_g[uu * 128 + d] = f2bf(Wq[d * 128 + uu] * 0.1275174346f);  // log2e/sqrt(128)
  else
    wt_g[(uu + 128) * 128 + d] = f2bf(Wk[d * 128 + uu]);
}

// ---------------------------------------------------------------------------
// qk_gemm: [q|k] = bf16(x) @ wt_g^T, output in FRAG-MAJOR layout. (unchanged)
// ---------------------------------------------------------------------------
__global__ __launch_bounds__(256, 2) void qk_gemm(
    const float* __restrict__ x, const ushort_t* __restrict__ wt_g,
    uint4* __restrict__ qF, uint4* __restrict__ kF) {
  __shared__ ushort_t xs[64 * LDST];
  __shared__ ushort_t sc[64 * SCT];
  const int tid = threadIdx.x, wave = tid >> 6, lane = tid & 63;
  const int lq = lane & 15, quad = lane >> 4;
  const int m0 = blockIdx.x * 64;

#pragma unroll
  for (int i = 0; i < 8; ++i) {  // stage x: 64x128 fp32 -> bf16
    int idx = i * 256 + tid;
    int row = idx >> 5, c4 = (idx & 31) * 4;
    const float4 v = *(const float4*)(x + (size_t)(m0 + row) * DD + c4);
    ushort4 h;
    h.x = f2bf(v.x); h.y = f2bf(v.y); h.z = f2bf(v.z); h.w = f2bf(v.w);
    *(ushort4*)(&xs[row * LDST + c4]) = h;
  }
  bf16x8 wf[4][4];  // wave's 64 output cols, K=128
#pragma unroll
  for (int nt = 0; nt < 4; ++nt)
#pragma unroll
    for (int ks = 0; ks < 4; ++ks)
      wf[nt][ks] = *(const bf16x8*)(wt_g + (wave * 64 + nt * 16 + lq) * 128 + ks * 32 + quad * 8);
  __syncthreads();

  f32x4 acc[4][4];
#pragma unroll
  for (int mt = 0; mt < 4; ++mt)
#pragma unroll
    for (int nt = 0; nt < 4; ++nt) acc[mt][nt] = (f32x4){0.f, 0.f, 0.f, 0.f};
#pragma unroll
  for (int mt = 0; mt < 4; ++mt) {
    bf16x8 af[4];
#pragma unroll
    for (int ks = 0; ks < 4; ++ks)
      af[ks] = *(const bf16x8*)(&xs[(mt * 16 + lq) * LDST + ks * 32 + quad * 8]);
#pragma unroll
    for (int nt = 0; nt < 4; ++nt)
#pragma unroll
      for (int ks = 0; ks < 4; ++ks)
        acc[mt][nt] = __builtin_amdgcn_mfma_f32_16x16x32_bf16(af[ks], wf[nt][ks], acc[mt][nt], 0, 0, 0);
  }
#pragma unroll
  for (int mt = 0; mt < 4; ++mt)
#pragma unroll
    for (int nt = 0; nt < 4; ++nt)
#pragma unroll
      for (int r = 0; r < 4; ++r)
        sc[(mt * 16 + quad * 4 + r) * SCT + wave * 64 + nt * 16 + lq] = f2bf(acc[mt][nt][r]);
  __syncthreads();
#pragma unroll
  for (int i = 0; i < 8; ++i) {
    int c = i * 256 + tid;                 // 0..2047
    int lane_c = c & 63, ks_c = (c >> 6) & 3, g_c = (c >> 8) & 3, isk = c >> 10;
    int li = lane_c & 15, qd = lane_c >> 4;
    int col = isk * 128 + ks_c * 32 + qd * 8;
    uint4 v = *(const uint4*)(&sc[(g_c * 16 + li) * SCT + col]);
    size_t G = (size_t)blockIdx.x * 4 + g_c;
    uint4* dst = isk ? kF : qF;
    dst[(G * 4 + ks_c) * 64 + lane_c] = v;
  }
}

// ---------------------------------------------------------------------------
// attn_fused: R8 base (XCD-chunked, depth-2 counted-vmcnt, 42.6 us,
// FETCH 8.4 MB) + THE ROUND-10 CHANGE: instruction-level MFMA||VALU
// interleave pinned by sched_group_barrier.
//
// R9 verdict: per-pass time invariant to occupancy/HBM/L2-bytes/LDS/
// depth -> limiter is per-wave structure. Corrected per-SIMD rates:
// 16x16x32 MFMA ~16 cyc/SIMD -> group = ~256 cyc MFMA + ~260 cyc VALU
// bursts that ALTERNATE (MfmaUtil 32 ~ VALUBusy 33, stall ~35%).
// Fix: dual accumulators (aA/aB, statically named); while the MFMAs of
// group n+1 accumulate into aB, the exp2/accumulate of group n (aA) is
// interleaved 1 MFMA : 2 VALU via SGB so one wave feeds both pipes.
// ---------------------------------------------------------------------------
__global__ __launch_bounds__(256, 2) void attn_fused(
    const uint4* __restrict__ qF, const uint4* __restrict__ kF,
    const float* __restrict__ t, const float* __restrict__ theta,
    const float* __restrict__ mu, float* __restrict__ w) {
  const int xcd = blockIdx.x & 7, s = blockIdx.x >> 3;  // wgid%8 -> XCD
  const int b = xcd + ((s >> 5) << 3);
  const int ib = s & 31;
  const int i0 = ib * 64;
  const int tid = threadIdx.x, wave = tid >> 6, lane = tid & 63;
  const int lq = lane & 15, quad = lane >> 4;

  __shared__ float rs_lds[4][64];
  __shared__ float c_lds[64];

  const bf16x8* qc = (const bf16x8*)qF;
  bf16x8 af[4][4];
#pragma unroll
  for (int mt = 0; mt < 4; ++mt)
#pragma unroll
    for (int ks = 0; ks < 4; ++ks)
      af[mt][ks] = qc[((size_t)(b * 128 + ib * 4 + mt) * 4 + ks) * 64 + lane];

  const bf16x8* kb = (const bf16x8*)kF + (size_t)b * 128 * 4 * 64 + lane;
  auto loadg = [&](bf16x8 (&f)[4], int g) {
#pragma unroll
    for (int ks = 0; ks < 4; ++ks)
      f[ks] = kb[((size_t)g * 4 + ks) * 64];
  };
  auto G = [&](int m) { return (m >> 1) * 8 + wave * 2 + (m & 1); };

  const f32x4 z4 = {0.f, 0.f, 0.f, 0.f};
  auto mfma16 = [&](f32x4 (&a)[4], bf16x8 (&f)[4]) {
#pragma unroll
    for (int mt = 0; mt < 4; ++mt)
      a[mt] = __builtin_amdgcn_mfma_f32_16x16x32_bf16(af[mt][0], f[0], z4, 0, 0, 0);
#pragma unroll
    for (int ks = 1; ks < 4; ++ks)
#pragma unroll
      for (int mt = 0; mt < 4; ++mt)
        a[mt] = __builtin_amdgcn_mfma_f32_16x16x32_bf16(af[mt][ks], f[ks], a[mt], 0, 0, 0);
  };

  float rowsum[4][4];
#pragma unroll
  for (int mt = 0; mt < 4; ++mt)
#pragma unroll
    for (int r = 0; r < 4; ++r) rowsum[mt][r] = 0.f;
  auto proc1 = [&](f32x4 (&a)[4]) {
#pragma unroll
    for (int mt = 0; mt < 4; ++mt)
#pragma unroll
      for (int r = 0; r < 4; ++r) rowsum[mt][r] += fexp2(a[mt][r]);
  };
  // Interleaved: MFMA group -> ad, consume as (16 exp2 + 16 add), pinned.
  auto step1 = [&](f32x4 (&ad)[4], bf16x8 (&f)[4], f32x4 (&as)[4]) {
    __builtin_amdgcn_s_setprio(1);
    mfma16(ad, f);
    proc1(as);
    SGB_MFMA1_VALU2();
    __builtin_amdgcn_s_setprio(0);
  };

  bf16x8 fA[4], fB[4];
  f32x4 aA[4], aB[4];

  // ---- PASS 1: row sums ----
  loadg(fA, G(0));
  loadg(fB, G(1));                       // 8 loads in flight
  WAITV(4); SB0();
  mfma16(aA, fA);                        // prologue (no consume)
  loadg(fA, G(2)); SB0();
  for (int m = 0; m < 30; m += 2) {
    WAITV(4); SB0();                     // fB landed
    step1(aB, fB, aA);                   // mfma G(m+1) || exp2 G(m)
    loadg(fB, G(m + 3)); SB0();
    WAITV(4); SB0();                     // fA landed
    step1(aA, fA, aB);                   // mfma G(m+2) || exp2 G(m+1)
    if (m < 28) { loadg(fA, G(m + 4)); }
    SB0();
  }
  WAITV(0); SB0();
  step1(aB, fB, aA);                     // mfma G(31) || exp2 G(30)
  SB0();
  proc1(aB);                             // exp2 G(31)

#pragma unroll
  for (int d2 = 1; d2 <= 8; d2 <<= 1)
#pragma unroll
    for (int mt = 0; mt < 4; ++mt)
#pragma unroll
      for (int r = 0; r < 4; ++r)
        rowsum[mt][r] += __shfl_xor(rowsum[mt][r], d2, 64);
  if (lq == 0) {
#pragma unroll
    for (int mt = 0; mt < 4; ++mt)
#pragma unroll
      for (int r = 0; r < 4; ++r)
        rs_lds[wave][mt * 16 + quad * 4 + r] = rowsum[mt][r];
  }
  __syncthreads();
  if (tid < 64) {
    float l = rs_lds[0][tid] + rs_lds[1][tid] + rs_lds[2][tid] + rs_lds[3][tid];
    int gi = i0 + tid;
    float z = theta[gi] - mu[gi] * t[b * SS + gi];
    float tf = 1.f / (1.f + fexp2(-z * 1.44269504f));
    c_lds[tid] = tf / l;
  }
  __syncthreads();
  float creg[4][4];
#pragma unroll
  for (int mt = 0; mt < 4; ++mt)
#pragma unroll
    for (int r = 0; r < 4; ++r) creg[mt][r] = c_lds[mt * 16 + quad * 4 + r];

  // pass-2 consume: 16 exp2 + 16 fmaf into 4 partial chains, then
  // (outside the pinned region) reduce + shuffles + atomic.
  auto proc2 = [&](f32x4 (&a)[4], int g) {
    float c0 = 0.f, c1 = 0.f, c2 = 0.f, c3 = 0.f;
#pragma unroll
    for (int mt = 0; mt < 4; ++mt) {
      c0 = fmaf(creg[mt][0], fexp2(a[mt][0]), c0);
      c1 = fmaf(creg[mt][1], fexp2(a[mt][1]), c1);
      c2 = fmaf(creg[mt][2], fexp2(a[mt][2]), c2);
      c3 = fmaf(creg[mt][3], fexp2(a[mt][3]), c3);
    }
    float cs = (c0 + c1) + (c2 + c3);
    cs += __shfl_xor(cs, 16, 64);
    cs += __shfl_xor(cs, 32, 64);
    if (lane < 16) atomicAdd(&w[b * SS + g * 16 + lane], cs);
  };
  auto step2 = [&](f32x4 (&ad)[4], bf16x8 (&f)[4], f32x4 (&as)[4], int g) {
    __builtin_amdgcn_s_setprio(1);
    mfma16(ad, f);
    proc2(as, g);
    SGB_MFMA1_VALU2();
    __builtin_amdgcn_s_setprio(0);
  };

  // ---- PASS 2: column sums -> w ----
  loadg(fA, G(0));
  loadg(fB, G(1));
  WAITV(4); SB0();
  mfma16(aA, fA);
  loadg(fA, G(2)); SB0();
  for (int m = 0; m < 30; m += 2) {
    WAITV(4); SB0();
    step2(aB, fB, aA, G(m));             // mfma G(m+1) || consume G(m)
    loadg(fB, G(m + 3)); SB0();
    WAITV(4); SB0();
    step2(aA, fA, aB, G(m + 1));         // mfma G(m+2) || consume G(m+1)
    if (m < 28) { loadg(fA, G(m + 4)); }
    SB0();
  }
  WAITV(0); SB0();
  step2(aB, fB, aA, G(30));
  SB0();
  proc2(aB, G(31));
}

// ---------------------------------------------------------------------------
// finalize: v[b,d] = sum_j w[b,j] * x[b,j,d].  grid 512. (R8 version)
// ---------------------------------------------------------------------------
__global__ __launch_bounds__(256) void finalize(
    const float* __restrict__ x, const float* __restrict__ w,
    float* __restrict__ out) {
  const int b = blockIdx.x >> 5;
  const int j0 = (blockIdx.x & 31) * 64;
  const int tid = threadIdx.x;
  const int d4 = (tid & 31) * 4, jo = tid >> 5;  // 32 d-groups x 8 j-offsets
  float4 a0 = {0.f, 0.f, 0.f, 0.f}, a1 = {0.f, 0.f, 0.f, 0.f};
#pragma unroll
  for (int jj = 0; jj < 4; ++jj) {
    int ja = j0 + jj * 16 + jo, jb = ja + 8;
    float wa = w[b * SS + ja], wb = w[b * SS + jb];
    const float4 xa = *(const float4*)(x + ((size_t)b * SS + ja) * DD + d4);
    const float4 xb = *(const float4*)(x + ((size_t)b * SS + jb) * DD + d4);
    a0.x = fmaf(wa, xa.x, a0.x); a0.y = fmaf(wa, xa.y, a0.y);
    a0.z = fmaf(wa, xa.z, a0.z); a0.w = fmaf(wa, xa.w, a0.w);
    a1.x = fmaf(wb, xb.x, a1.x); a1.y = fmaf(wb, xb.y, a1.y);
    a1.z = fmaf(wb, xb.z, a1.z); a1.w = fmaf(wb, xb.w, a1.w);
  }
  __shared__ float4 red[256];
  float4 acc = {a0.x + a1.x, a0.y + a1.y, a0.z + a1.z, a0.w + a1.w};
  red[tid] = acc;
  __syncthreads();
  if (tid < 128) {
    float4 o = red[tid + 128];
    red[tid].x += o.x; red[tid].y += o.y; red[tid].z += o.z; red[tid].w += o.w;
  }
  __syncthreads();
  if (tid < 64) {
    float4 o = red[tid + 64];
    red[tid].x += o.x; red[tid].y += o.y; red[tid].z += o.z; red[tid].w += o.w;
  }
  __syncthreads();
  if (tid < 32) {
    float4 v = red[tid], o = red[tid + 32];
    v.x += o.x; v.y += o.y; v.z += o.z; v.w += o.w;
    atomicAdd(&out[b * DD + d4 + 0], v.x);
    atomicAdd(&out[b * DD + d4 + 1], v.y);
    atomicAdd(&out[b * DD + d4 + 2], v.z);
    atomicAdd(&out[b * DD + d4 + 3], v.w);
  }
}

extern "C" void kernel_launch(void* const* d_in, const int* in_sizes, int n_in,
                              void* d_out, int out_size, void* d_ws, size_t ws_size,
                              hipStream_t stream) {
  const float* x = (const float*)d_in[0];
  const float* t = (const float*)d_in[1];
  const float* Wq = (const float*)d_in[2];
  const float* Wk = (const float*)d_in[3];
  const float* theta = (const float*)d_in[4];
  const float* mu = (const float*)d_in[5];
  float* out = (float*)d_out;

  uint4* qF = (uint4*)d_ws;                             // 8.4 MB (frag-major)
  uint4* kF = qF + (size_t)2048 * 4 * 64;               // 8.4 MB (frag-major)
  ushort_t* wt_g = (ushort_t*)(kF + (size_t)2048 * 4 * 64);  // 64 KB
  float* w = (float*)(wt_g + 256 * 128);                // 128 KB

  hipMemsetAsync(w, 0, (size_t)BB * SS * sizeof(float), stream);
  hipMemsetAsync(d_out, 0, (size_t)BB * DD * sizeof(float), stream);

  wprep<<<dim3(128), dim3(256), 0, stream>>>(Wq, Wk, wt_g);
  qk_gemm<<<dim3(512), dim3(256), 0, stream>>>(x, wt_g, qF, kF);
  attn_fused<<<dim3(512), dim3(256), 0, stream>>>(qF, kF, t, theta, mu, w);
  finalize<<<dim3(512), dim3(256), 0, stream>>>(x, w, out);
}

// Round 11
// 127.493 us; speedup vs baseline: 1.0243x; 1.0158x over previous
//
#include <hip/hip_runtime.h>
#include <hip/hip_bf16.h>

#define SS 2048
#define DD 128
#define BB 16
#define LDST 136  // xs staging pad (ushorts)
#define SCT2 134  // sc stride for 128-col half (bf16), gcd(3,32)=1 row shift

typedef short bf16x8 __attribute__((ext_vector_type(8)));
typedef float f32x4 __attribute__((ext_vector_type(4)));
typedef unsigned short ushort_t;

#define SB0() __builtin_amdgcn_sched_barrier(0)
#define WAITV(n) asm volatile("s_waitcnt vmcnt(" #n ")" ::: "memory")

__device__ __forceinline__ unsigned short f2bf(float f) {
  union { float f; unsigned u; } v; v.f = f;
  unsigned r = v.u + 0x7fffu + ((v.u >> 16) & 1u);  // RNE
  return (unsigned short)(r >> 16);
}
__device__ __forceinline__ float fexp2(float x) { return __builtin_amdgcn_exp2f(x); }

// Fragment-major layout: chunk index ((G*4 + ks)*64 + lane), 16 B each.
// G = global 16-row group (b*128 + g), lane = quad*16 + lq holds
// rows[G*16+lq], cols[ks*32+quad*8 .. +8].

// ---------------------------------------------------------------------------
// wprep: wt_g = [Wq^T * log2e/sqrt(U) ; Wk^T] bf16 [256][128].
// R11: proper LDS tile transpose — old version read W at stride 512 B/lane
// (uncoalesced, ~64x fetch amplification). grid 8 = isK(2) x ut(2) x dt(2),
// 64x64 tiles; both global read and write fully coalesced.
// ---------------------------------------------------------------------------
__global__ __launch_bounds__(256) void wprep(
    const float* __restrict__ Wq, const float* __restrict__ Wk,
    ushort_t* __restrict__ wt_g) {
  const int isK = blockIdx.x >> 2, ut = (blockIdx.x >> 1) & 1, dt = blockIdx.x & 1;
  const int tid = threadIdx.x;
  const float* W = isK ? Wk : Wq;
  const float scale = isK ? 1.0f : 0.1275174346f;  // log2e/sqrt(128)
  __shared__ float tile[64][65];

  // read: 64 d-rows x 64 uu, coalesced along uu
  {
    int uu = tid & 63, dr = tid >> 6;  // 4 rows per pass
#pragma unroll
    for (int p = 0; p < 16; ++p) {
      int d = p * 4 + dr;
      tile[uu][d] = W[(size_t)(dt * 64 + d) * 128 + ut * 64 + uu];
    }
  }
  __syncthreads();
  // write: 64 uu-rows x 64 d, coalesced along d
  {
    int d = tid & 63, ur = tid >> 6;
#pragma unroll
    for (int p = 0; p < 16; ++p) {
      int uu = p * 4 + ur;
      wt_g[(size_t)(isK * 128 + ut * 64 + uu) * 128 + dt * 64 + d] =
          f2bf(tile[uu][d] * scale);
    }
  }
}

// ---------------------------------------------------------------------------
// qk_gemm: [q|k] = bf16(x) @ wt_g^T, FRAG-MAJOR output.
// R11 redesign: 27-31 us inferred from session budget = 5-10x roofline.
// Old: 512 blocks at 2/CU, three serialized barrier phases, ~93% stall.
// New: 64 rows x 128 cols per block (ch selects Q- or K-half), wf 32 +
// acc 32 regs -> launch_bounds(256,4) -> grid 1024, 4 blocks/CU: double
// TLP overlaps the stage/MFMA/transpose phases across blocks. x read 2x
// (+16 MB ~ +2.5 us HBM) -- cheap vs the stall. LDS 17+17.5 KB x4 = 138.
// ---------------------------------------------------------------------------
__global__ __launch_bounds__(256, 4) void qk_gemm(
    const float* __restrict__ x, const ushort_t* __restrict__ wt_g,
    uint4* __restrict__ qF, uint4* __restrict__ kF) {
  __shared__ ushort_t xs[64 * LDST];
  __shared__ ushort_t sc[64 * SCT2];
  const int tid = threadIdx.x, wave = tid >> 6, lane = tid & 63;
  const int lq = lane & 15, quad = lane >> 4;
  const int rb = blockIdx.x >> 1, ch = blockIdx.x & 1;
  const int m0 = rb * 64;

  // stage x: 64x128 fp32 -> bf16 (two halves, SB0 caps live loads)
#pragma unroll
  for (int i = 0; i < 4; ++i) {
    int idx = i * 256 + tid;
    int row = idx >> 5, c4 = (idx & 31) * 4;
    const float4 v = *(const float4*)(x + (size_t)(m0 + row) * DD + c4);
    ushort4 h;
    h.x = f2bf(v.x); h.y = f2bf(v.y); h.z = f2bf(v.z); h.w = f2bf(v.w);
    *(ushort4*)(&xs[row * LDST + c4]) = h;
  }
  SB0();
#pragma unroll
  for (int i = 4; i < 8; ++i) {
    int idx = i * 256 + tid;
    int row = idx >> 5, c4 = (idx & 31) * 4;
    const float4 v = *(const float4*)(x + (size_t)(m0 + row) * DD + c4);
    ushort4 h;
    h.x = f2bf(v.x); h.y = f2bf(v.y); h.z = f2bf(v.z); h.w = f2bf(v.w);
    *(ushort4*)(&xs[row * LDST + c4]) = h;
  }
  // wave's 32 output cols (within this ch half), K=128
  bf16x8 wf[2][4];
#pragma unroll
  for (int nt = 0; nt < 2; ++nt)
#pragma unroll
    for (int ks = 0; ks < 4; ++ks)
      wf[nt][ks] = *(const bf16x8*)(wt_g +
          (size_t)(ch * 128 + wave * 32 + nt * 16 + lq) * 128 + ks * 32 + quad * 8);
  __syncthreads();

  f32x4 acc[4][2];
#pragma unroll
  for (int mt = 0; mt < 4; ++mt)
#pragma unroll
    for (int nt = 0; nt < 2; ++nt) acc[mt][nt] = (f32x4){0.f, 0.f, 0.f, 0.f};
#pragma unroll
  for (int mt = 0; mt < 4; ++mt) {
    bf16x8 af[4];
#pragma unroll
    for (int ks = 0; ks < 4; ++ks)
      af[ks] = *(const bf16x8*)(&xs[(mt * 16 + lq) * LDST + ks * 32 + quad * 8]);
#pragma unroll
    for (int nt = 0; nt < 2; ++nt)
#pragma unroll
      for (int ks = 0; ks < 4; ++ks)
        acc[mt][nt] = __builtin_amdgcn_mfma_f32_16x16x32_bf16(af[ks], wf[nt][ks], acc[mt][nt], 0, 0, 0);
  }
  // C/D: row = mt*16+quad*4+r, col(half-local) = wave*32+nt*16+lq
#pragma unroll
  for (int mt = 0; mt < 4; ++mt)
#pragma unroll
    for (int nt = 0; nt < 2; ++nt)
#pragma unroll
      for (int r = 0; r < 4; ++r)
        sc[(mt * 16 + quad * 4 + r) * SCT2 + wave * 32 + nt * 16 + lq] = f2bf(acc[mt][nt][r]);
  __syncthreads();
  // epilogue: frag-order re-read, coalesced frag-major store (1024 chunks)
#pragma unroll
  for (int i = 0; i < 4; ++i) {
    int c = i * 256 + tid;                 // 0..1023
    int lane_c = c & 63, ks_c = (c >> 6) & 3, g_c = (c >> 8) & 3;
    int li = lane_c & 15, qd = lane_c >> 4;
    int col = ks_c * 32 + qd * 8;
    uint4 v = *(const uint4*)(&sc[(g_c * 16 + li) * SCT2 + col]);
    size_t G = (size_t)rb * 4 + g_c;
    uint4* dst = ch ? kF : qF;
    dst[(G * 4 + ks_c) * 64 + lane_c] = v;
  }
}

// ---------------------------------------------------------------------------
// attn_fused: EXACT R8 form (session best: 42.6 us, FETCH 8.4 MB, VGPR 76).
// XCD-chunked decode + depth-2 counted-vmcnt pipeline. R10's SGB variant
// reverted (44.0, neutral-negative).
// ---------------------------------------------------------------------------
__global__ __launch_bounds__(256, 2) void attn_fused(
    const uint4* __restrict__ qF, const uint4* __restrict__ kF,
    const float* __restrict__ t, const float* __restrict__ theta,
    const float* __restrict__ mu, float* __restrict__ w) {
  const int xcd = blockIdx.x & 7, s = blockIdx.x >> 3;  // wgid%8 -> XCD
  const int b = xcd + ((s >> 5) << 3);
  const int ib = s & 31;
  const int i0 = ib * 64;
  const int tid = threadIdx.x, wave = tid >> 6, lane = tid & 63;
  const int lq = lane & 15, quad = lane >> 4;

  __shared__ float rs_lds[4][64];
  __shared__ float c_lds[64];

  const bf16x8* qc = (const bf16x8*)qF;
  bf16x8 af[4][4];
#pragma unroll
  for (int mt = 0; mt < 4; ++mt)
#pragma unroll
    for (int ks = 0; ks < 4; ++ks)
      af[mt][ks] = qc[((size_t)(b * 128 + ib * 4 + mt) * 4 + ks) * 64 + lane];

  const bf16x8* kb = (const bf16x8*)kF + (size_t)b * 128 * 4 * 64 + lane;
  auto loadg = [&](bf16x8 (&f)[4], int g) {
#pragma unroll
    for (int ks = 0; ks < 4; ++ks)
      f[ks] = kb[((size_t)g * 4 + ks) * 64];
  };
  auto G = [&](int m) { return (m >> 1) * 8 + wave * 2 + (m & 1); };

  const f32x4 z4 = {0.f, 0.f, 0.f, 0.f};
  auto mfma16 = [&](f32x4 (&a)[4], bf16x8 (&f)[4]) {
    __builtin_amdgcn_s_setprio(1);
#pragma unroll
    for (int mt = 0; mt < 4; ++mt)
      a[mt] = __builtin_amdgcn_mfma_f32_16x16x32_bf16(af[mt][0], f[0], z4, 0, 0, 0);
#pragma unroll
    for (int ks = 1; ks < 4; ++ks)
#pragma unroll
      for (int mt = 0; mt < 4; ++mt)
        a[mt] = __builtin_amdgcn_mfma_f32_16x16x32_bf16(af[mt][ks], f[ks], a[mt], 0, 0, 0);
    __builtin_amdgcn_s_setprio(0);
  };

  float rowsum[4][4];
#pragma unroll
  for (int mt = 0; mt < 4; ++mt)
#pragma unroll
    for (int r = 0; r < 4; ++r) rowsum[mt][r] = 0.f;
  auto proc1 = [&](f32x4 (&a)[4]) {
#pragma unroll
    for (int mt = 0; mt < 4; ++mt)
#pragma unroll
      for (int r = 0; r < 4; ++r) rowsum[mt][r] += fexp2(a[mt][r]);
  };

  bf16x8 fA[4], fB[4];
  f32x4 a[4];

  // ---- PASS 1: row sums (depth-2 counted-vmcnt pipeline) ----
  loadg(fA, G(0));
  loadg(fB, G(1));                       // 8 loads in flight
  for (int m = 0; m < 30; m += 2) {
    WAITV(4); SB0();                     // oldest 4 (fA) landed
    mfma16(a, fA);
    loadg(fA, G(m + 2)); SB0();          // refill while exp2 runs
    proc1(a);
    WAITV(4); SB0();
    mfma16(a, fB);
    loadg(fB, G(m + 3)); SB0();
    proc1(a);
  }
  WAITV(4); SB0(); mfma16(a, fA); SB0(); proc1(a);
  WAITV(0); SB0(); mfma16(a, fB); SB0(); proc1(a);

#pragma unroll
  for (int d2 = 1; d2 <= 8; d2 <<= 1)
#pragma unroll
    for (int mt = 0; mt < 4; ++mt)
#pragma unroll
      for (int r = 0; r < 4; ++r)
        rowsum[mt][r] += __shfl_xor(rowsum[mt][r], d2, 64);
  if (lq == 0) {
#pragma unroll
    for (int mt = 0; mt < 4; ++mt)
#pragma unroll
      for (int r = 0; r < 4; ++r)
        rs_lds[wave][mt * 16 + quad * 4 + r] = rowsum[mt][r];
  }
  __syncthreads();
  if (tid < 64) {
    float l = rs_lds[0][tid] + rs_lds[1][tid] + rs_lds[2][tid] + rs_lds[3][tid];
    int gi = i0 + tid;
    float z = theta[gi] - mu[gi] * t[b * SS + gi];
    float tf = 1.f / (1.f + fexp2(-z * 1.44269504f));
    c_lds[tid] = tf / l;
  }
  __syncthreads();
  float creg[4][4];
#pragma unroll
  for (int mt = 0; mt < 4; ++mt)
#pragma unroll
    for (int r = 0; r < 4; ++r) creg[mt][r] = c_lds[mt * 16 + quad * 4 + r];

  auto proc2 = [&](f32x4 (&aa)[4], int g) {
    float cs = 0.f;
#pragma unroll
    for (int mt = 0; mt < 4; ++mt)
#pragma unroll
      for (int r = 0; r < 4; ++r) cs = fmaf(creg[mt][r], fexp2(aa[mt][r]), cs);
    cs += __shfl_xor(cs, 16, 64);
    cs += __shfl_xor(cs, 32, 64);
    if (lane < 16) atomicAdd(&w[b * SS + g * 16 + lane], cs);
  };

  // ---- PASS 2: column sums -> w (same pipeline; af reused) ----
  loadg(fA, G(0));
  loadg(fB, G(1));
  for (int m = 0; m < 30; m += 2) {
    WAITV(4); SB0();
    mfma16(a, fA);
    loadg(fA, G(m + 2)); SB0();
    proc2(a, G(m));
    WAITV(4); SB0();
    mfma16(a, fB);
    loadg(fB, G(m + 3)); SB0();
    proc2(a, G(m + 1));
  }
  WAITV(4); SB0(); mfma16(a, fA); SB0(); proc2(a, G(30));
  WAITV(0); SB0(); mfma16(a, fB); SB0(); proc2(a, G(31));
}

// ---------------------------------------------------------------------------
// finalize: v[b,d] = sum_j w[b,j] * x[b,j,d].  grid 512. (R8 version)
// ---------------------------------------------------------------------------
__global__ __launch_bounds__(256) void finalize(
    const float* __restrict__ x, const float* __restrict__ w,
    float* __restrict__ out) {
  const int b = blockIdx.x >> 5;
  const int j0 = (blockIdx.x & 31) * 64;
  const int tid = threadIdx.x;
  const int d4 = (tid & 31) * 4, jo = tid >> 5;  // 32 d-groups x 8 j-offsets
  float4 a0 = {0.f, 0.f, 0.f, 0.f}, a1 = {0.f, 0.f, 0.f, 0.f};
#pragma unroll
  for (int jj = 0; jj < 4; ++jj) {
    int ja = j0 + jj * 16 + jo, jb = ja + 8;
    float wa = w[b * SS + ja], wb = w[b * SS + jb];
    const float4 xa = *(const float4*)(x + ((size_t)b * SS + ja) * DD + d4);
    const float4 xb = *(const float4*)(x + ((size_t)b * SS + jb) * DD + d4);
    a0.x = fmaf(wa, xa.x, a0.x); a0.y = fmaf(wa, xa.y, a0.y);
    a0.z = fmaf(wa, xa.z, a0.z); a0.w = fmaf(wa, xa.w, a0.w);
    a1.x = fmaf(wb, xb.x, a1.x); a1.y = fmaf(wb, xb.y, a1.y);
    a1.z = fmaf(wb, xb.z, a1.z); a1.w = fmaf(wb, xb.w, a1.w);
  }
  __shared__ float4 red[256];
  float4 acc = {a0.x + a1.x, a0.y + a1.y, a0.z + a1.z, a0.w + a1.w};
  red[tid] = acc;
  __syncthreads();
  if (tid < 128) {
    float4 o = red[tid + 128];
    red[tid].x += o.x; red[tid].y += o.y; red[tid].z += o.z; red[tid].w += o.w;
  }
  __syncthreads();
  if (tid < 64) {
    float4 o = red[tid + 64];
    red[tid].x += o.x; red[tid].y += o.y; red[tid].z += o.z; red[tid].w += o.w;
  }
  __syncthreads();
  if (tid < 32) {
    float4 v = red[tid], o = red[tid + 32];
    v.x += o.x; v.y += o.y; v.z += o.z; v.w += o.w;
    atomicAdd(&out[b * DD + d4 + 0], v.x);
    atomicAdd(&out[b * DD + d4 + 1], v.y);
    atomicAdd(&out[b * DD + d4 + 2], v.z);
    atomicAdd(&out[b * DD + d4 + 3], v.w);
  }
}

extern "C" void kernel_launch(void* const* d_in, const int* in_sizes, int n_in,
                              void* d_out, int out_size, void* d_ws, size_t ws_size,
                              hipStream_t stream) {
  const float* x = (const float*)d_in[0];
  const float* t = (const float*)d_in[1];
  const float* Wq = (const float*)d_in[2];
  const float* Wk = (const float*)d_in[3];
  const float* theta = (const float*)d_in[4];
  const float* mu = (const float*)d_in[5];
  float* out = (float*)d_out;

  uint4* qF = (uint4*)d_ws;                             // 8.4 MB (frag-major)
  uint4* kF = qF + (size_t)2048 * 4 * 64;               // 8.4 MB (frag-major)
  ushort_t* wt_g = (ushort_t*)(kF + (size_t)2048 * 4 * 64);  // 64 KB
  float* w = (float*)(wt_g + 256 * 128);                // 128 KB

  hipMemsetAsync(w, 0, (size_t)BB * SS * sizeof(float), stream);
  hipMemsetAsync(d_out, 0, (size_t)BB * DD * sizeof(float), stream);

  wprep<<<dim3(8), dim3(256), 0, stream>>>(Wq, Wk, wt_g);
  qk_gemm<<<dim3(1024), dim3(256), 0, stream>>>(x, wt_g, qF, kF);
  attn_fused<<<dim3(512), dim3(256), 0, stream>>>(qF, kF, t, theta, mu, w);
  finalize<<<dim3(512), dim3(256), 0, stream>>>(x, w, out);
}